// Round 3
// baseline (120.708 us; speedup 1.0000x reference)
//
#include <hip/hip_runtime.h>
#include <math.h>

#define B_ 2
#define L_ 2048
#define C_ 1024
#define H_ 16
#define D_ 64
#define BH_ (B_*H_)      // 32
#define M_ (B_*L_)       // 4096
#define N_ (3*C_)        // 3072
#define K_ C_            // 1024
#define EPS_ 1e-6f
#define NCHUNK_ 16       // L-split for k2b

typedef unsigned short ushort_t;
typedef short short8 __attribute__((ext_vector_type(8)));
typedef float f32x4 __attribute__((ext_vector_type(4)));
typedef unsigned short ushort4_t __attribute__((ext_vector_type(4)));

__device__ __forceinline__ ushort_t f2bf(float f) {
    union { float f; unsigned u; } v; v.f = f;
    unsigned r = v.u + 0x7FFFu + ((v.u >> 16) & 1u);
    return (ushort_t)(r >> 16);
}
__device__ __forceinline__ float bf2f(ushort_t h) {
    union { unsigned u; float f; } v; v.u = ((unsigned)h) << 16;
    return v.f;
}

__device__ __forceinline__ void gload16(const void* g, void* l) {
    __builtin_amdgcn_global_load_lds(
        (const __attribute__((address_space(1))) void*)g,
        (__attribute__((address_space(3))) void*)l, 16, 0, 0);
}

// ---------------- cast: hidden + Wq/Wk/Wv -> bf16 ----------------
__global__ __launch_bounds__(256) void cast_kernel(
    const float* __restrict__ hs, const float* __restrict__ Wq,
    const float* __restrict__ Wk, const float* __restrict__ Wv,
    ushort_t* __restrict__ hsB, ushort_t* __restrict__ Wcat) {
    const int NH = M_ * K_ / 4;        // 1048576 chunks of 4
    const int NW = (C_ * C_) / 4;      // 262144 per weight
    const int total = NH + 3 * NW;
    for (int i = blockIdx.x * blockDim.x + threadIdx.x; i < total;
         i += gridDim.x * blockDim.x) {
        const float* src; ushort_t* dst; int off;
        if (i < NH) { src = hs; dst = hsB; off = i * 4; }
        else {
            int j = i - NH; int m = j >> 18; int r = j - (m << 18);
            src = (m == 0 ? Wq : (m == 1 ? Wk : Wv));
            dst = Wcat + (size_t)m * (C_ * C_); off = r * 4;
        }
        f32x4 v = *(const f32x4*)(src + off);
        ushort4_t o;
        o.x = f2bf(v.x); o.y = f2bf(v.y); o.z = f2bf(v.z); o.w = f2bf(v.w);
        *(ushort4_t*)(dst + off) = o;
    }
}

// ---------------- eta = sigmoid(hs . lr_w + lr_b)/D : [BH, L] ----------------
__global__ __launch_bounds__(1024) void eta_kernel(
    const float* __restrict__ hs, const float* __restrict__ lrw,
    const float* __restrict__ lrb, float* __restrict__ eta) {
    int i = blockIdx.x;               // b*L + l
    int b = i >> 11, l = i & (L_ - 1);
    int t = threadIdx.x, h = t >> 6, lane = t & 63;
    const float* row = hs + (size_t)i * C_;
    const float* wrow = lrw + h * C_;
    float s = 0.f;
    #pragma unroll
    for (int k0 = 0; k0 < C_; k0 += 256) {
        f32x4 a = *(const f32x4*)(row + k0 + lane * 4);
        f32x4 w = *(const f32x4*)(wrow + k0 + lane * 4);
        s += a.x * w.x + a.y * w.y + a.z * w.z + a.w * w.w;
    }
    #pragma unroll
    for (int m = 32; m; m >>= 1) s += __shfl_xor(s, m, 64);
    if (lane == 0) {
        float x = s + lrb[h];
        float sig = 1.f / (1.f + expf(-x));
        eta[((size_t)(b * H_ + h)) * L_ + l] = sig * (1.0f / 64.0f);
    }
}

// ---------------- projection GEMM: [4096,1024] @ Wcat[3072,1024]^T ----------------
// BK=64, XOR-swizzled LDS (slot ^= row&7 on 16B slots); staging pre-swizzles
// the GLOBAL source column (LDS dest linear, as global_load_lds requires).
__global__ __launch_bounds__(256) void gemm_qkv(
    const ushort_t* __restrict__ A, const ushort_t* __restrict__ Bc,
    ushort_t* __restrict__ XQ, ushort_t* __restrict__ XK,
    ushort_t* __restrict__ XV, ushort_t* __restrict__ XKt) {
    __shared__ __align__(16) ushort_t Al[128 * 64];
    __shared__ __align__(16) ushort_t Bl[128 * 64];
    const int bm = blockIdx.x, bn = blockIdx.y;
    const int t = threadIdx.x, w = t >> 6, lane = t & 63;
    const int wr = w >> 1, wc = w & 1;
    f32x4 acc[4][4];
    #pragma unroll
    for (int a = 0; a < 4; a++)
        #pragma unroll
        for (int b = 0; b < 4; b++)
            #pragma unroll
            for (int j = 0; j < 4; j++) acc[a][b][j] = 0.f;

    // staging geometry: 16B unit li = it*256 + w*64 + lane, it in [0,4)
    // r = li>>3 (row 0..127), slot = li&7, src slot = slot ^ (r&7)
    const int srow = (w << 3) + (lane >> 3);      // + it*32
    const int sslot0 = lane & 7;
    // fragment read rows
    const int fr_a = wr * 64 + (lane & 15);       // + mf*16
    const int fr_b = wc * 64 + (lane & 15);       // + nf*16

    for (int kt = 0; kt < K_ / 64; ++kt) {
        __syncthreads();
        #pragma unroll
        for (int it = 0; it < 4; ++it) {
            int r = it * 32 + srow;
            int sslot = sslot0 ^ (r & 7);
            const size_t gcol = (size_t)kt * 64 + sslot * 8;
            gload16(A + (size_t)(bm * 128 + r) * K_ + gcol,
                    &Al[(it * 256 + w * 64) * 8]);
            gload16(Bc + (size_t)(bn * 128 + r) * K_ + gcol,
                    &Bl[(it * 256 + w * 64) * 8]);
        }
        __syncthreads();
        #pragma unroll
        for (int ks = 0; ks < 2; ++ks) {
            short8 af[4], bfv[4];
            #pragma unroll
            for (int mf = 0; mf < 4; ++mf) {
                int r = fr_a + mf * 16;
                int slot = (ks * 4 + (lane >> 4)) ^ (r & 7);
                af[mf] = *(const short8*)&Al[r * 64 + slot * 8];
            }
            #pragma unroll
            for (int nf = 0; nf < 4; ++nf) {
                int r = fr_b + nf * 16;
                int slot = (ks * 4 + (lane >> 4)) ^ (r & 7);
                bfv[nf] = *(const short8*)&Bl[r * 64 + slot * 8];
            }
            #pragma unroll
            for (int mf = 0; mf < 4; ++mf)
                #pragma unroll
                for (int nf = 0; nf < 4; ++nf)
                    acc[mf][nf] = __builtin_amdgcn_mfma_f32_16x16x32_bf16(
                        af[mf], bfv[nf], acc[mf][nf], 0, 0, 0);
        }
    }

    const int jbase = bn * 128;
    const int mtx = jbase >> 10;
    ushort_t* dst = (mtx == 0) ? XQ : (mtx == 1 ? XK : XV);
    #pragma unroll
    for (int mf = 0; mf < 4; ++mf)
        #pragma unroll
        for (int nf = 0; nf < 4; ++nf)
            #pragma unroll
            for (int rg = 0; rg < 4; ++rg) {
                int i = bm * 128 + wr * 64 + mf * 16 + ((lane >> 4) << 2) + rg;
                int j = (jbase & 1023) + wc * 64 + nf * 16 + (lane & 15);
                int b = i >> 11, l = i & (L_ - 1);
                int h = j >> 6, d = j & 63;
                ushort_t bv = f2bf(acc[mf][nf][rg]);
                dst[((size_t)(b * H_ + h) * L_ + l) * D_ + d] = bv;
                if (mtx == 1)
                    XKt[((size_t)(b * H_ + h) * D_ + d) * L_ + l] = bv;
            }
}

// ---------------- K2: Z1 = XK@W1+b1, LN-L2-bwd, eg = eta*grad -> egT ----------------
__global__ __launch_bounds__(256) void k2_grad(
    const ushort_t* __restrict__ XK, const ushort_t* __restrict__ XV,
    const float* __restrict__ W1, const float* __restrict__ b1,
    const float* __restrict__ tw, const float* __restrict__ tb,
    const float* __restrict__ eta, ushort_t* __restrict__ egT) {
    __shared__ __align__(16) ushort_t W1t[64 * 64];
    __shared__ float b1s[64], gs[64], bes[64];
    const int bh = blockIdx.y, lt = blockIdx.x;
    const int h = bh & (H_ - 1);
    const int t = threadIdx.x, w = t >> 6, lane = t & 63;
    for (int p = t; p < 4096; p += 256) {
        int e = p >> 6, f = p & 63;
        W1t[f * 64 + e] = f2bf(W1[h * 4096 + p]);
    }
    if (t < 64) { b1s[t] = b1[h * 64 + t]; gs[t] = tw[h * 64 + t]; bes[t] = tb[h * 64 + t]; }
    __syncthreads();

    const ushort_t* xk = XK + (size_t)bh * L_ * D_;
    const ushort_t* xv = XV + (size_t)bh * L_ * D_;
    const int l0 = lt * 128 + w * 32;

    f32x4 acc[2][4];
    #pragma unroll
    for (int mf = 0; mf < 2; mf++)
        #pragma unroll
        for (int nf = 0; nf < 4; nf++) {
            float bv = b1s[nf * 16 + (lane & 15)];
            #pragma unroll
            for (int j = 0; j < 4; j++) acc[mf][nf][j] = bv;
        }
    #pragma unroll
    for (int ks = 0; ks < 2; ++ks) {
        short8 af[2], bfv[4];
        #pragma unroll
        for (int mf = 0; mf < 2; mf++)
            af[mf] = *(const short8*)&xk[(size_t)(l0 + mf * 16 + (lane & 15)) * D_ + ks * 32 + (lane >> 4) * 8];
        #pragma unroll
        for (int nf = 0; nf < 4; nf++)
            bfv[nf] = *(const short8*)&W1t[(nf * 16 + (lane & 15)) * 64 + ks * 32 + (lane >> 4) * 8];
        #pragma unroll
        for (int mf = 0; mf < 2; mf++)
            #pragma unroll
            for (int nf = 0; nf < 4; nf++)
                acc[mf][nf] = __builtin_amdgcn_mfma_f32_16x16x32_bf16(
                    af[mf], bfv[nf], acc[mf][nf], 0, 0, 0);
    }

    const float* etap = eta + (size_t)bh * L_;
    #pragma unroll
    for (int mf = 0; mf < 2; ++mf) {
        #pragma unroll
        for (int rg = 0; rg < 4; ++rg) {
            int lrow = l0 + mf * 16 + ((lane >> 4) << 2) + rg;
            float x[4], xh[4], gh[4];
            #pragma unroll
            for (int nf = 0; nf < 4; nf++) x[nf] = acc[mf][nf][rg];
            float s = x[0] + x[1] + x[2] + x[3];
            s += __shfl_xor(s, 1, 64); s += __shfl_xor(s, 2, 64);
            s += __shfl_xor(s, 4, 64); s += __shfl_xor(s, 8, 64);
            float mu = s * (1.f / 64.f);
            float vs = 0.f;
            #pragma unroll
            for (int nf = 0; nf < 4; nf++) { float dd = x[nf] - mu; vs += dd * dd; }
            vs += __shfl_xor(vs, 1, 64); vs += __shfl_xor(vs, 2, 64);
            vs += __shfl_xor(vs, 4, 64); vs += __shfl_xor(vs, 8, 64);
            float stdv = sqrtf(vs * (1.f / 64.f) + EPS_);
            float inv = 1.f / stdv;
            float s1 = 0.f, s2 = 0.f;
            #pragma unroll
            for (int nf = 0; nf < 4; nf++) {
                int d = nf * 16 + (lane & 15);
                xh[nf] = (x[nf] - mu) * inv;
                float tgt = bf2f(xv[(size_t)lrow * D_ + d]) - bf2f(xk[(size_t)lrow * D_ + d]);
                float g = gs[d];
                gh[nf] = (g * xh[nf] + bes[d] - tgt) * g;
                s1 += gh[nf]; s2 += gh[nf] * xh[nf];
            }
            s1 += __shfl_xor(s1, 1, 64); s1 += __shfl_xor(s1, 2, 64);
            s1 += __shfl_xor(s1, 4, 64); s1 += __shfl_xor(s1, 8, 64);
            s2 += __shfl_xor(s2, 1, 64); s2 += __shfl_xor(s2, 2, 64);
            s2 += __shfl_xor(s2, 4, 64); s2 += __shfl_xor(s2, 8, 64);
            float m1 = s1 * (1.f / 64.f), m2 = s2 * (1.f / 64.f);
            float el = etap[lrow];
            #pragma unroll
            for (int nf = 0; nf < 4; nf++) {
                int d = nf * 16 + (lane & 15);
                float z = (gh[nf] - m1 - xh[nf] * m2) * inv;
                egT[((size_t)bh * D_ + d) * L_ + lrow] = f2bf(el * z);
            }
        }
    }
}

// ---------------- K2b-part: partial G over an L-chunk of 128, + partial bsum ----------------
__global__ __launch_bounds__(256) void k2b_part(
    const ushort_t* __restrict__ XKt, const ushort_t* __restrict__ egT,
    float* __restrict__ Gp, float* __restrict__ bsump) {
    const int chunk = blockIdx.x, bh = blockIdx.y;
    const int t = threadIdx.x, w = t >> 6, lane = t & 63;
    const ushort_t* xkt = XKt + (size_t)bh * D_ * L_;
    const ushort_t* egt = egT + (size_t)bh * D_ * L_;
    f32x4 acc[4];
    #pragma unroll
    for (int nf = 0; nf < 4; nf++)
        #pragma unroll
        for (int j = 0; j < 4; j++) acc[nf][j] = 0.f;
    #pragma unroll
    for (int ki = 0; ki < 4; ++ki) {
        int kt = chunk * 4 + ki;
        short8 af = *(const short8*)&xkt[(size_t)(w * 16 + (lane & 15)) * L_ + kt * 32 + (lane >> 4) * 8];
        short8 bfv[4];
        #pragma unroll
        for (int nf = 0; nf < 4; nf++)
            bfv[nf] = *(const short8*)&egt[(size_t)(nf * 16 + (lane & 15)) * L_ + kt * 32 + (lane >> 4) * 8];
        #pragma unroll
        for (int nf = 0; nf < 4; nf++)
            acc[nf] = __builtin_amdgcn_mfma_f32_16x16x32_bf16(af, bfv[nf], acc[nf], 0, 0, 0);
    }
    float* gp = Gp + (size_t)(bh * NCHUNK_ + chunk) * 4096;
    #pragma unroll
    for (int nf = 0; nf < 4; nf++)
        #pragma unroll
        for (int rg = 0; rg < 4; rg++) {
            int e = w * 16 + ((lane >> 4) << 2) + rg;
            int d = nf * 16 + (lane & 15);
            gp[e * 64 + d] = acc[nf][rg];
        }
    // partial column sum of eg over this chunk (fixed order -> deterministic)
    __shared__ float sred[4][64];
    int dd = t & 63, q = t >> 6;
    float s = 0.f;
    const ushort_t* rowp = egt + (size_t)dd * L_ + chunk * 128 + q * 32;
    #pragma unroll
    for (int k = 0; k < 32; k += 8) {
        short8 v = *(const short8*)&rowp[k];
        #pragma unroll
        for (int j = 0; j < 8; j++) s += bf2f((ushort_t)v[j]);
    }
    sred[q][dd] = s;
    __syncthreads();
    if (t < 64)
        bsump[(bh * NCHUNK_ + chunk) * 64 + t] =
            sred[0][t] + sred[1][t] + sred[2][t] + sred[3][t];
}

// ---------------- K2b-reduce: G = sum_c Gp, bsum = sum_c bsump (fixed order) ----------------
__global__ __launch_bounds__(256) void k2b_reduce(
    const float* __restrict__ Gp, const float* __restrict__ bsump,
    float* __restrict__ G, float* __restrict__ bsum) {
    const int seg = blockIdx.x, bh = blockIdx.y;   // seg in [0,8)
    const int t = threadIdx.x;
    #pragma unroll 2
    for (int ii = 0; ii < 2; ++ii) {
        int i = seg * 512 + ii * 256 + t;
        float s = 0.f;
        #pragma unroll
        for (int c = 0; c < NCHUNK_; c++)
            s += Gp[(size_t)(bh * NCHUNK_ + c) * 4096 + i];
        G[(size_t)bh * 4096 + i] = s;
    }
    if (seg == 0 && t < 64) {
        float s = 0.f;
        #pragma unroll
        for (int c = 0; c < NCHUNK_; c++)
            s += bsump[(bh * NCHUNK_ + c) * 64 + t];
        bsum[bh * 64 + t] = s;
    }
}

// ---------------- K3: Z1b = XQ@(W1-G)+b1bar, LN-fwd, out = XQ + LN ----------------
__global__ __launch_bounds__(256) void k3_out(
    const ushort_t* __restrict__ XQ, const float* __restrict__ W1,
    const float* __restrict__ G, const float* __restrict__ b1,
    const float* __restrict__ bsum, const float* __restrict__ tw,
    const float* __restrict__ tb, float* __restrict__ out) {
    __shared__ __align__(16) ushort_t Wt[64 * 64];
    __shared__ float b1s[64], gs[64], bes[64];
    const int bh = blockIdx.y, lt = blockIdx.x;
    const int h = bh & (H_ - 1);
    const int t = threadIdx.x, w = t >> 6, lane = t & 63;
    for (int p = t; p < 4096; p += 256) {
        int e = p >> 6, f = p & 63;
        Wt[f * 64 + e] = f2bf(W1[h * 4096 + p] - G[(size_t)bh * 4096 + p]);
    }
    if (t < 64) {
        b1s[t] = b1[h * 64 + t] - bsum[bh * 64 + t];
        gs[t] = tw[h * 64 + t]; bes[t] = tb[h * 64 + t];
    }
    __syncthreads();

    const ushort_t* xq = XQ + (size_t)bh * L_ * D_;
    const int l0 = lt * 128 + w * 32;
    f32x4 acc[2][4];
    #pragma unroll
    for (int mf = 0; mf < 2; mf++)
        #pragma unroll
        for (int nf = 0; nf < 4; nf++) {
            float bv = b1s[nf * 16 + (lane & 15)];
            #pragma unroll
            for (int j = 0; j < 4; j++) acc[mf][nf][j] = bv;
        }
    #pragma unroll
    for (int ks = 0; ks < 2; ++ks) {
        short8 af[2], bfv[4];
        #pragma unroll
        for (int mf = 0; mf < 2; mf++)
            af[mf] = *(const short8*)&xq[(size_t)(l0 + mf * 16 + (lane & 15)) * D_ + ks * 32 + (lane >> 4) * 8];
        #pragma unroll
        for (int nf = 0; nf < 4; nf++)
            bfv[nf] = *(const short8*)&Wt[(nf * 16 + (lane & 15)) * 64 + ks * 32 + (lane >> 4) * 8];
        #pragma unroll
        for (int mf = 0; mf < 2; mf++)
            #pragma unroll
            for (int nf = 0; nf < 4; nf++)
                acc[mf][nf] = __builtin_amdgcn_mfma_f32_16x16x32_bf16(
                    af[mf], bfv[nf], acc[mf][nf], 0, 0, 0);
    }

    float* outp = out + (size_t)bh * L_ * D_;
    #pragma unroll
    for (int mf = 0; mf < 2; ++mf) {
        #pragma unroll
        for (int rg = 0; rg < 4; ++rg) {
            int lrow = l0 + mf * 16 + ((lane >> 4) << 2) + rg;
            float x[4];
            #pragma unroll
            for (int nf = 0; nf < 4; nf++) x[nf] = acc[mf][nf][rg];
            float s = x[0] + x[1] + x[2] + x[3];
            s += __shfl_xor(s, 1, 64); s += __shfl_xor(s, 2, 64);
            s += __shfl_xor(s, 4, 64); s += __shfl_xor(s, 8, 64);
            float mu = s * (1.f / 64.f);
            float vs = 0.f;
            #pragma unroll
            for (int nf = 0; nf < 4; nf++) { float dd = x[nf] - mu; vs += dd * dd; }
            vs += __shfl_xor(vs, 1, 64); vs += __shfl_xor(vs, 2, 64);
            vs += __shfl_xor(vs, 4, 64); vs += __shfl_xor(vs, 8, 64);
            float inv = 1.f / sqrtf(vs * (1.f / 64.f) + EPS_);
            #pragma unroll
            for (int nf = 0; nf < 4; nf++) {
                int d = nf * 16 + (lane & 15);
                float xh = (x[nf] - mu) * inv;
                float o = gs[d] * xh + bes[d];
                float qv = bf2f(xq[(size_t)lrow * D_ + d]);
                outp[(size_t)lrow * D_ + d] = qv + o;
            }
        }
    }
}

extern "C" void kernel_launch(void* const* d_in, const int* in_sizes, int n_in,
                              void* d_out, int out_size, void* d_ws, size_t ws_size,
                              hipStream_t stream) {
    const float* hs  = (const float*)d_in[0];
    const float* Wq  = (const float*)d_in[1];
    const float* Wk  = (const float*)d_in[2];
    const float* Wv  = (const float*)d_in[3];
    const float* W1  = (const float*)d_in[4];
    const float* b1  = (const float*)d_in[5];
    const float* tw  = (const float*)d_in[6];
    const float* tb  = (const float*)d_in[7];
    const float* lrw = (const float*)d_in[8];
    const float* lrb = (const float*)d_in[9];
    float* out = (float*)d_out;

    char* ws = (char*)d_ws;
    size_t off = 0;
    ushort_t* hsB  = (ushort_t*)(ws + off); off += (size_t)M_ * K_ * 2;        // 8 MB
    ushort_t* Wcat = (ushort_t*)(ws + off); off += (size_t)N_ * K_ * 2;        // 6 MB
    ushort_t* XQ   = (ushort_t*)(ws + off); off += (size_t)M_ * C_ * 2;
    ushort_t* XK   = (ushort_t*)(ws + off); off += (size_t)M_ * C_ * 2;
    ushort_t* XV   = (ushort_t*)(ws + off); off += (size_t)M_ * C_ * 2;
    ushort_t* XKt  = (ushort_t*)(ws + off); off += (size_t)M_ * C_ * 2;
    ushort_t* egT  = (ushort_t*)(ws + off); off += (size_t)M_ * C_ * 2;
    float*    eta  = (float*)(ws + off);    off += (size_t)BH_ * L_ * 4;
    float*    G    = (float*)(ws + off);    off += (size_t)BH_ * D_ * D_ * 4;
    float*    bsum = (float*)(ws + off);    off += (size_t)BH_ * D_ * 4;
    // Partial buffers overlay hsB/Wcat: both are dead after gemm_qkv, and
    // k2b_part runs strictly later on the same stream.
    float*    Gp    = (float*)hsB;   // 32*16*4096*4 = 8 MB == sizeof(hsB)
    float*    bsump = (float*)Wcat;  // 128 KB << 6 MB

    cast_kernel<<<2048, 256, 0, stream>>>(hs, Wq, Wk, Wv, hsB, Wcat);
    eta_kernel<<<M_, 1024, 0, stream>>>(hs, lrw, lrb, eta);
    gemm_qkv<<<dim3(M_ / 128, N_ / 128), 256, 0, stream>>>(hsB, Wcat, XQ, XK, XV, XKt);
    k2_grad<<<dim3(L_ / 128, BH_), 256, 0, stream>>>(XK, XV, W1, b1, tw, tb, eta, egT);
    k2b_part<<<dim3(NCHUNK_, BH_), 256, 0, stream>>>(XKt, egT, Gp, bsump);
    k2b_reduce<<<dim3(8, BH_), 256, 0, stream>>>(Gp, bsump, G, bsum);
    k3_out<<<dim3(L_ / 128, BH_), 256, 0, stream>>>(XQ, W1, G, b1, bsum, tw, tb, out);
}

// Round 4
// 80.730 us; speedup vs baseline: 1.4952x; 1.4952x over previous
//
#include <hip/hip_runtime.h>
#include <math.h>

#define B_ 2
#define L_ 2048
#define C_ 1024
#define H_ 16
#define D_ 64
#define BH_ (B_*H_)      // 32
#define M_ (B_*L_)       // 4096
#define N_ (3*C_)        // 3072
#define K_ C_            // 1024
#define EPS_ 1e-6f
#define NCHUNK_ 16       // L-split for G partials
#define LDT_ 136         // padded LDS row stride (shorts): 272B = 17*16, 16B-aligned, 2-way banks

typedef unsigned short ushort_t;
typedef short short8 __attribute__((ext_vector_type(8)));
typedef float f32x4 __attribute__((ext_vector_type(4)));
typedef unsigned short ushort4_t __attribute__((ext_vector_type(4)));

__device__ __forceinline__ ushort_t f2bf(float f) {
    union { float f; unsigned u; } v; v.f = f;
    unsigned r = v.u + 0x7FFFu + ((v.u >> 16) & 1u);
    return (ushort_t)(r >> 16);
}
__device__ __forceinline__ float bf2f(ushort_t h) {
    union { unsigned u; float f; } v; v.u = ((unsigned)h) << 16;
    return v.f;
}

__device__ __forceinline__ void gload16(const void* g, void* l) {
    __builtin_amdgcn_global_load_lds(
        (const __attribute__((address_space(1))) void*)g,
        (__attribute__((address_space(3))) void*)l, 16, 0, 0);
}

// ---------------- cast hs+weights -> bf16, fused eta ----------------
// blocks 0..2047: two hs rows each (cast + 16 head-dots); blocks 2048..2815: weight cast
__global__ __launch_bounds__(256) void cast_eta(
    const float* __restrict__ hs, const float* __restrict__ Wq,
    const float* __restrict__ Wk, const float* __restrict__ Wv,
    const float* __restrict__ lrw, const float* __restrict__ lrb,
    ushort_t* __restrict__ hsB, ushort_t* __restrict__ Wcat,
    float* __restrict__ eta) {
    __shared__ float pA[16][257], pB[16][257];
    const int bid = blockIdx.x, t = threadIdx.x;
    if (bid < 2048) {
        const int iA = bid * 2, iB = iA + 1;
        const float* rA = hs + (size_t)iA * C_;
        const float* rB = hs + (size_t)iB * C_;
        f32x4 a = *(const f32x4*)(rA + t * 4);
        f32x4 b = *(const f32x4*)(rB + t * 4);
        ushort4_t oa, ob;
        oa.x = f2bf(a.x); oa.y = f2bf(a.y); oa.z = f2bf(a.z); oa.w = f2bf(a.w);
        ob.x = f2bf(b.x); ob.y = f2bf(b.y); ob.z = f2bf(b.z); ob.w = f2bf(b.w);
        *(ushort4_t*)(hsB + (size_t)iA * C_ + t * 4) = oa;
        *(ushort4_t*)(hsB + (size_t)iB * C_ + t * 4) = ob;
        #pragma unroll
        for (int h = 0; h < 16; ++h) {
            f32x4 w = *(const f32x4*)(lrw + (size_t)h * C_ + t * 4);
            pA[h][t] = a.x * w.x + a.y * w.y + a.z * w.z + a.w * w.w;
            pB[h][t] = b.x * w.x + b.y * w.y + b.z * w.z + b.w * w.w;
        }
        __syncthreads();
        const int h = t >> 4, seg = t & 15;
        float sA = 0.f, sB = 0.f;
        #pragma unroll
        for (int j = 0; j < 16; ++j) {
            sA += pA[h][seg * 16 + j];
            sB += pB[h][seg * 16 + j];
        }
        #pragma unroll
        for (int m = 1; m < 16; m <<= 1) {
            sA += __shfl_xor(sA, m, 64);
            sB += __shfl_xor(sB, m, 64);
        }
        if (seg == 0) {
            float bb = lrb[h];
            int bA = iA >> 11, lA = iA & (L_ - 1);
            int bB = iB >> 11, lB = iB & (L_ - 1);
            eta[((size_t)(bA * H_ + h)) * L_ + lA] =
                (1.f / (1.f + expf(-(sA + bb)))) * (1.0f / 64.0f);
            eta[((size_t)(bB * H_ + h)) * L_ + lB] =
                (1.f / (1.f + expf(-(sB + bb)))) * (1.0f / 64.0f);
        }
    } else {
        const int wb = bid - 2048;   // 0..767
        #pragma unroll
        for (int ii = 0; ii < 4; ++ii) {
            int cid = wb * 1024 + ii * 256 + t;      // 0..786431
            int m = cid >> 18, r = cid & ((1 << 18) - 1);
            const float* src = (m == 0 ? Wq : (m == 1 ? Wk : Wv));
            f32x4 v = *(const f32x4*)(src + (size_t)r * 4);
            ushort4_t o;
            o.x = f2bf(v.x); o.y = f2bf(v.y); o.z = f2bf(v.z); o.w = f2bf(v.w);
            *(ushort4_t*)(Wcat + (size_t)m * (C_ * C_) + (size_t)r * 4) = o;
        }
    }
}

// ---------------- projection GEMM: [4096,1024] @ Wcat[3072,1024]^T ----------------
// BK=32 (16 KB LDS, R2 occupancy), 2-way XOR swizzle: slot ^= (row>>1)&3.
// Staging pre-swizzles the GLOBAL source column (LDS dest linear); read-side
// XOR is a per-thread constant. No XKt store.
__global__ __launch_bounds__(256) void gemm_qkv(
    const ushort_t* __restrict__ A, const ushort_t* __restrict__ Bc,
    ushort_t* __restrict__ XQ, ushort_t* __restrict__ XK,
    ushort_t* __restrict__ XV) {
    __shared__ __align__(16) ushort_t Al[128 * 32];
    __shared__ __align__(16) ushort_t Bl[128 * 32];
    const int bm = blockIdx.x, bn = blockIdx.y;
    const int t = threadIdx.x, w = t >> 6, lane = t & 63;
    const int wr = w >> 1, wc = w & 1;
    f32x4 acc[4][4];
    #pragma unroll
    for (int a = 0; a < 4; a++)
        #pragma unroll
        for (int b = 0; b < 4; b++)
            #pragma unroll
            for (int j = 0; j < 4; j++) acc[a][b][j] = 0.f;

    const int ci0 = w * 64 + lane;
    const int xread = ((lane & 15) >> 1) & 3;        // read-side swizzle (const/thread)
    const int uslot = (lane >> 4) ^ xread;           // swizzled 16B unit for frags

    for (int kt = 0; kt < K_ / 32; ++kt) {
        __syncthreads();
        #pragma unroll
        for (int q = 0; q < 2; ++q) {
            int ci = q * 256 + ci0;
            int r = ci >> 2, kc = ci & 3;
            int kcp = kc ^ ((r >> 1) & 3);           // pre-swizzled source column
            gload16(A + (size_t)(bm * 128 + r) * K_ + kt * 32 + kcp * 8,
                    &Al[q * 2048 + w * 512]);
            gload16(Bc + (size_t)(bn * 128 + r) * K_ + kt * 32 + kcp * 8,
                    &Bl[q * 2048 + w * 512]);
        }
        __syncthreads();
        short8 af[4], bfv[4];
        #pragma unroll
        for (int mf = 0; mf < 4; ++mf)
            af[mf] = *(const short8*)&Al[(wr * 64 + mf * 16 + (lane & 15)) * 32 + uslot * 8];
        #pragma unroll
        for (int nf = 0; nf < 4; ++nf)
            bfv[nf] = *(const short8*)&Bl[(wc * 64 + nf * 16 + (lane & 15)) * 32 + uslot * 8];
        #pragma unroll
        for (int mf = 0; mf < 4; ++mf)
            #pragma unroll
            for (int nf = 0; nf < 4; ++nf)
                acc[mf][nf] = __builtin_amdgcn_mfma_f32_16x16x32_bf16(
                    af[mf], bfv[nf], acc[mf][nf], 0, 0, 0);
    }

    const int jbase = bn * 128;
    const int mtx = jbase >> 10;
    ushort_t* dst = (mtx == 0) ? XQ : (mtx == 1 ? XK : XV);
    #pragma unroll
    for (int mf = 0; mf < 4; ++mf)
        #pragma unroll
        for (int nf = 0; nf < 4; ++nf)
            #pragma unroll
            for (int rg = 0; rg < 4; ++rg) {
                int i = bm * 128 + wr * 64 + mf * 16 + ((lane >> 4) << 2) + rg;
                int j = (jbase & 1023) + wc * 64 + nf * 16 + (lane & 15);
                int b = i >> 11, l = i & (L_ - 1);
                int h = j >> 6, d = j & 63;
                dst[((size_t)(b * H_ + h) * L_ + l) * D_ + d] = f2bf(acc[mf][nf][rg]);
            }
}

// ---------------- K2 fused: Z1 = XK@W1+b1, LN-L2-bwd, eg = eta*grad,
//                  Gp = XK_chunk^T @ eg_chunk (MFMA over LDS), bsump ----------------
__global__ __launch_bounds__(256) void k2_grad2(
    const ushort_t* __restrict__ XK, const ushort_t* __restrict__ XV,
    const float* __restrict__ W1, const float* __restrict__ b1,
    const float* __restrict__ tw, const float* __restrict__ tb,
    const float* __restrict__ eta, float* __restrict__ Gp,
    float* __restrict__ bsump) {
    __shared__ __align__(16) ushort_t W1t[64 * 64];
    __shared__ __align__(16) ushort_t xkt[64 * LDT_];   // XK^T (d-major, l-contig)
    __shared__ __align__(16) ushort_t egl[64 * LDT_];   // eg^T (d-major, l-contig)
    __shared__ float b1s[64], gs[64], bes[64];
    __shared__ float sred[4][64];
    const int bh = blockIdx.y, lt = blockIdx.x;
    const int h = bh & (H_ - 1);
    const int t = threadIdx.x, w = t >> 6, lane = t & 63;
    for (int p = t; p < 4096; p += 256) {
        int e = p >> 6, f = p & 63;
        W1t[f * 64 + e] = f2bf(W1[h * 4096 + p]);
    }
    if (t < 64) { b1s[t] = b1[h * 64 + t]; gs[t] = tw[h * 64 + t]; bes[t] = tb[h * 64 + t]; }
    __syncthreads();

    const ushort_t* xk = XK + (size_t)bh * L_ * D_;
    const ushort_t* xv = XV + (size_t)bh * L_ * D_;
    const int l0 = lt * 128 + w * 32;    // global l base for this wave
    const int llw = w * 32;              // local l base

    f32x4 acc[2][4];
    #pragma unroll
    for (int mf = 0; mf < 2; mf++)
        #pragma unroll
        for (int nf = 0; nf < 4; nf++) {
            float bv = b1s[nf * 16 + (lane & 15)];
            #pragma unroll
            for (int j = 0; j < 4; j++) acc[mf][nf][j] = bv;
        }
    #pragma unroll
    for (int ks = 0; ks < 2; ++ks) {
        short8 af[2], bfv[4];
        const int d0 = ks * 32 + (lane >> 4) * 8;
        #pragma unroll
        for (int mf = 0; mf < 2; mf++) {
            af[mf] = *(const short8*)&xk[(size_t)(l0 + mf * 16 + (lane & 15)) * D_ + d0];
            const int ll = llw + mf * 16 + (lane & 15);
            #pragma unroll
            for (int jj = 0; jj < 8; jj++)
                xkt[(d0 + jj) * LDT_ + ll] = (ushort_t)af[mf][jj];
        }
        #pragma unroll
        for (int nf = 0; nf < 4; nf++)
            bfv[nf] = *(const short8*)&W1t[(nf * 16 + (lane & 15)) * 64 + d0];
        #pragma unroll
        for (int mf = 0; mf < 2; mf++)
            #pragma unroll
            for (int nf = 0; nf < 4; nf++)
                acc[mf][nf] = __builtin_amdgcn_mfma_f32_16x16x32_bf16(
                    af[mf], bfv[nf], acc[mf][nf], 0, 0, 0);
    }

    const float* etap = eta + (size_t)bh * L_;
    float accbs[4] = {0.f, 0.f, 0.f, 0.f};
    #pragma unroll
    for (int mf = 0; mf < 2; ++mf) {
        #pragma unroll
        for (int rg = 0; rg < 4; ++rg) {
            int lrow = l0 + mf * 16 + ((lane >> 4) << 2) + rg;
            int llr  = llw + mf * 16 + ((lane >> 4) << 2) + rg;
            float x[4], xh[4], gh[4];
            #pragma unroll
            for (int nf = 0; nf < 4; nf++) x[nf] = acc[mf][nf][rg];
            float s = x[0] + x[1] + x[2] + x[3];
            s += __shfl_xor(s, 1, 64); s += __shfl_xor(s, 2, 64);
            s += __shfl_xor(s, 4, 64); s += __shfl_xor(s, 8, 64);
            float mu = s * (1.f / 64.f);
            float vs = 0.f;
            #pragma unroll
            for (int nf = 0; nf < 4; nf++) { float dd = x[nf] - mu; vs += dd * dd; }
            vs += __shfl_xor(vs, 1, 64); vs += __shfl_xor(vs, 2, 64);
            vs += __shfl_xor(vs, 4, 64); vs += __shfl_xor(vs, 8, 64);
            float inv = 1.f / sqrtf(vs * (1.f / 64.f) + EPS_);
            float s1 = 0.f, s2 = 0.f;
            #pragma unroll
            for (int nf = 0; nf < 4; nf++) {
                int d = nf * 16 + (lane & 15);
                xh[nf] = (x[nf] - mu) * inv;
                float tgt = bf2f(xv[(size_t)lrow * D_ + d]) - bf2f(xk[(size_t)lrow * D_ + d]);
                float g = gs[d];
                gh[nf] = (g * xh[nf] + bes[d] - tgt) * g;
                s1 += gh[nf]; s2 += gh[nf] * xh[nf];
            }
            s1 += __shfl_xor(s1, 1, 64); s1 += __shfl_xor(s1, 2, 64);
            s1 += __shfl_xor(s1, 4, 64); s1 += __shfl_xor(s1, 8, 64);
            s2 += __shfl_xor(s2, 1, 64); s2 += __shfl_xor(s2, 2, 64);
            s2 += __shfl_xor(s2, 4, 64); s2 += __shfl_xor(s2, 8, 64);
            float m1 = s1 * (1.f / 64.f), m2 = s2 * (1.f / 64.f);
            float el = etap[lrow];
            #pragma unroll
            for (int nf = 0; nf < 4; nf++) {
                int d = nf * 16 + (lane & 15);
                float egv = el * ((gh[nf] - m1 - xh[nf] * m2) * inv);
                accbs[nf] += egv;
                egl[d * LDT_ + llr] = f2bf(egv);
            }
        }
    }
    // wave-local bsum partial: combine the 4 row-groups (lane>>4)
    #pragma unroll
    for (int nf = 0; nf < 4; nf++) {
        accbs[nf] += __shfl_xor(accbs[nf], 16, 64);
        accbs[nf] += __shfl_xor(accbs[nf], 32, 64);
    }
    if (lane < 16)
        #pragma unroll
        for (int nf = 0; nf < 4; nf++) sred[w][nf * 16 + lane] = accbs[nf];
    __syncthreads();

    // G partial: Gp[e][d] = sum_{l in chunk} XK[l][e] * eg[l][d]; wave w owns e-range [16w,16w+16)
    f32x4 aG[4];
    #pragma unroll
    for (int nf = 0; nf < 4; nf++)
        #pragma unroll
        for (int j = 0; j < 4; j++) aG[nf][j] = 0.f;
    #pragma unroll
    for (int ks = 0; ks < 4; ++ks) {
        const int ko = ks * 32 + (lane >> 4) * 8;
        short8 ae = *(const short8*)&xkt[(w * 16 + (lane & 15)) * LDT_ + ko];
        #pragma unroll
        for (int nf = 0; nf < 4; nf++) {
            short8 be = *(const short8*)&egl[(nf * 16 + (lane & 15)) * LDT_ + ko];
            aG[nf] = __builtin_amdgcn_mfma_f32_16x16x32_bf16(ae, be, aG[nf], 0, 0, 0);
        }
    }
    float* gp = Gp + (size_t)(bh * NCHUNK_ + lt) * 4096;
    #pragma unroll
    for (int nf = 0; nf < 4; nf++)
        #pragma unroll
        for (int rg = 0; rg < 4; rg++) {
            int e = w * 16 + ((lane >> 4) << 2) + rg;
            int d = nf * 16 + (lane & 15);
            gp[e * 64 + d] = aG[nf][rg];
        }
    if (t < 64)
        bsump[(bh * NCHUNK_ + lt) * 64 + t] =
            sred[0][t] + sred[1][t] + sred[2][t] + sred[3][t];
}

// ---------------- K2b-reduce: G = sum_c Gp, bsum = sum_c bsump (fixed order) ----------------
__global__ __launch_bounds__(256) void k2b_reduce(
    const float* __restrict__ Gp, const float* __restrict__ bsump,
    float* __restrict__ G, float* __restrict__ bsum) {
    const int seg = blockIdx.x, bh = blockIdx.y;   // seg in [0,8)
    const int t = threadIdx.x;
    #pragma unroll 2
    for (int ii = 0; ii < 2; ++ii) {
        int i = seg * 512 + ii * 256 + t;
        float s = 0.f;
        #pragma unroll
        for (int c = 0; c < NCHUNK_; c++)
            s += Gp[(size_t)(bh * NCHUNK_ + c) * 4096 + i];
        G[(size_t)bh * 4096 + i] = s;
    }
    if (seg == 0 && t < 64) {
        float s = 0.f;
        #pragma unroll
        for (int c = 0; c < NCHUNK_; c++)
            s += bsump[(bh * NCHUNK_ + c) * 64 + t];
        bsum[bh * 64 + t] = s;
    }
}

// ---------------- K3: Z1b = XQ@(W1-G)+b1bar, LN-fwd, out = XQ + LN ----------------
__global__ __launch_bounds__(256) void k3_out(
    const ushort_t* __restrict__ XQ, const float* __restrict__ W1,
    const float* __restrict__ G, const float* __restrict__ b1,
    const float* __restrict__ bsum, const float* __restrict__ tw,
    const float* __restrict__ tb, float* __restrict__ out) {
    __shared__ __align__(16) ushort_t Wt[64 * 64];
    __shared__ float b1s[64], gs[64], bes[64];
    const int bh = blockIdx.y, lt = blockIdx.x;
    const int h = bh & (H_ - 1);
    const int t = threadIdx.x, w = t >> 6, lane = t & 63;
    for (int p = t; p < 4096; p += 256) {
        int e = p >> 6, f = p & 63;
        Wt[f * 64 + e] = f2bf(W1[h * 4096 + p] - G[(size_t)bh * 4096 + p]);
    }
    if (t < 64) {
        b1s[t] = b1[h * 64 + t] - bsum[bh * 64 + t];
        gs[t] = tw[h * 64 + t]; bes[t] = tb[h * 64 + t];
    }
    __syncthreads();

    const ushort_t* xq = XQ + (size_t)bh * L_ * D_;
    const int l0 = lt * 128 + w * 32;
    f32x4 acc[2][4];
    #pragma unroll
    for (int mf = 0; mf < 2; mf++)
        #pragma unroll
        for (int nf = 0; nf < 4; nf++) {
            float bv = b1s[nf * 16 + (lane & 15)];
            #pragma unroll
            for (int j = 0; j < 4; j++) acc[mf][nf][j] = bv;
        }
    #pragma unroll
    for (int ks = 0; ks < 2; ++ks) {
        short8 af[2], bfv[4];
        #pragma unroll
        for (int mf = 0; mf < 2; mf++)
            af[mf] = *(const short8*)&xq[(size_t)(l0 + mf * 16 + (lane & 15)) * D_ + ks * 32 + (lane >> 4) * 8];
        #pragma unroll
        for (int nf = 0; nf < 4; nf++)
            bfv[nf] = *(const short8*)&Wt[(nf * 16 + (lane & 15)) * 64 + ks * 32 + (lane >> 4) * 8];
        #pragma unroll
        for (int mf = 0; mf < 2; mf++)
            #pragma unroll
            for (int nf = 0; nf < 4; nf++)
                acc[mf][nf] = __builtin_amdgcn_mfma_f32_16x16x32_bf16(
                    af[mf], bfv[nf], acc[mf][nf], 0, 0, 0);
    }

    float* outp = out + (size_t)bh * L_ * D_;
    #pragma unroll
    for (int mf = 0; mf < 2; ++mf) {
        #pragma unroll
        for (int rg = 0; rg < 4; ++rg) {
            int lrow = l0 + mf * 16 + ((lane >> 4) << 2) + rg;
            float x[4];
            #pragma unroll
            for (int nf = 0; nf < 4; nf++) x[nf] = acc[mf][nf][rg];
            float s = x[0] + x[1] + x[2] + x[3];
            s += __shfl_xor(s, 1, 64); s += __shfl_xor(s, 2, 64);
            s += __shfl_xor(s, 4, 64); s += __shfl_xor(s, 8, 64);
            float mu = s * (1.f / 64.f);
            float vs = 0.f;
            #pragma unroll
            for (int nf = 0; nf < 4; nf++) { float dd = x[nf] - mu; vs += dd * dd; }
            vs += __shfl_xor(vs, 1, 64); vs += __shfl_xor(vs, 2, 64);
            vs += __shfl_xor(vs, 4, 64); vs += __shfl_xor(vs, 8, 64);
            float inv = 1.f / sqrtf(vs * (1.f / 64.f) + EPS_);
            #pragma unroll
            for (int nf = 0; nf < 4; nf++) {
                int d = nf * 16 + (lane & 15);
                float xh = (x[nf] - mu) * inv;
                float o = gs[d] * xh + bes[d];
                float qv = bf2f(xq[(size_t)lrow * D_ + d]);
                outp[(size_t)lrow * D_ + d] = qv + o;
            }
        }
    }
}

extern "C" void kernel_launch(void* const* d_in, const int* in_sizes, int n_in,
                              void* d_out, int out_size, void* d_ws, size_t ws_size,
                              hipStream_t stream) {
    const float* hs  = (const float*)d_in[0];
    const float* Wq  = (const float*)d_in[1];
    const float* Wk  = (const float*)d_in[2];
    const float* Wv  = (const float*)d_in[3];
    const float* W1  = (const float*)d_in[4];
    const float* b1  = (const float*)d_in[5];
    const float* tw  = (const float*)d_in[6];
    const float* tb  = (const float*)d_in[7];
    const float* lrw = (const float*)d_in[8];
    const float* lrb = (const float*)d_in[9];
    float* out = (float*)d_out;

    char* ws = (char*)d_ws;
    size_t off = 0;
    ushort_t* hsB  = (ushort_t*)(ws + off); off += (size_t)M_ * K_ * 2;   // 8 MB
    ushort_t* Wcat = (ushort_t*)(ws + off); off += (size_t)N_ * K_ * 2;   // 6 MB
    ushort_t* XQ   = (ushort_t*)(ws + off); off += (size_t)M_ * C_ * 2;
    ushort_t* XK   = (ushort_t*)(ws + off); off += (size_t)M_ * C_ * 2;
    ushort_t* XV   = (ushort_t*)(ws + off); off += (size_t)M_ * C_ * 2;
    float*    eta  = (float*)(ws + off);    off += (size_t)BH_ * L_ * 4;
    float*    G    = (float*)(ws + off);    off += (size_t)BH_ * D_ * D_ * 4;
    float*    bsum = (float*)(ws + off);    off += (size_t)BH_ * D_ * 4;
    // Partial buffers overlay hsB/Wcat: both dead after gemm_qkv; k2_grad2
    // writes them strictly later on the same stream.
    float*    Gp    = (float*)hsB;   // 32*16*4096*4 = 8 MB == sizeof(hsB)
    float*    bsump = (float*)Wcat;  // 128 KB << 6 MB

    cast_eta<<<2048 + 768, 256, 0, stream>>>(hs, Wq, Wk, Wv, lrw, lrb, hsB, Wcat, eta);
    gemm_qkv<<<dim3(M_ / 128, N_ / 128), 256, 0, stream>>>(hsB, Wcat, XQ, XK, XV);
    k2_grad2<<<dim3(L_ / 128, BH_), 256, 0, stream>>>(XK, XV, W1, b1, tw, tb, eta, Gp, bsump);
    k2b_reduce<<<dim3(8, BH_), 256, 0, stream>>>(Gp, bsump, G, bsum);
    k3_out<<<dim3(L_ / 128, BH_), 256, 0, stream>>>(XQ, W1, G, b1, bsum, tw, tb, out);
}